// Round 3
// baseline (293.453 us; speedup 1.0000x reference)
//
#include <hip/hip_runtime.h>
#include <cstdint>

// ============================================================================
// Fused MHA forward, MI355X/gfx950. f16 MFMA pipeline:
//   1. cvt_all: x fp32 -> Xb f16 (blocks < 8192); W,Wo -> WT/WoT transposed f16
//   2. gemm_qkv: QKV = Xb @ WT^T -> Qb,Kb (Q pre-scaled log2e/sqrt(128)),
//               V transposed via LDS -> VTb [bh][d][n]. 256x128 tiles,
//               4 waves x (128x64) per wave, mfma 32x32x16, BK=64, 48 KB LDS,
//               grid (32 m, 24 j) = 768 blocks = exactly 3/CU. m fastest ->
//               A-tiles pinned per-XCD.
//   3. flash:   32x32x16-MFMA flash, fixed-max (M=0) softmax, SWAPPED QK^T
//               (S^T = mfma(K,Q): lane&31 = q) so softmax + P-transpose run
//               fully in registers (cvt to f16 pairs + permlane32_swap,
//               no sP LDS round-trip). 256-thread blocks (4 waves x 32 q),
//               KV-tile 64, double-buffered sK/sVT (64 KB), ONE barrier/tile.
//               PV computes O^T = mfma(VT, P^T); epilogue transposes O via
//               reused sK LDS -> coalesced Oc. Grid (32 bh, 16 q) = 2/CU.
//   4. gemm_out: out = Oc @ WoT^T, 16x128 tiles, grid 512 = 2 blocks/CU.
// LDS XOR swizzle (16B chunk ^= row&7) everywhere; staging via
// global_load_lds width-16 with source-permuted addresses (dest lane-linear).
// ============================================================================

#define DEV __device__ __forceinline__

typedef _Float16 h8 __attribute__((ext_vector_type(8)));
typedef _Float16 h4 __attribute__((ext_vector_type(4)));
typedef _Float16 h2 __attribute__((ext_vector_type(2)));
typedef float f4 __attribute__((ext_vector_type(4)));
typedef float f16x16 __attribute__((ext_vector_type(16)));
typedef uint32_t u32x4 __attribute__((ext_vector_type(4)));
typedef uint32_t u32x2 __attribute__((ext_vector_type(2)));

typedef __attribute__((address_space(1))) const uint32_t gu32;
typedef __attribute__((address_space(3))) uint32_t lu32;

DEV float fexp2(float x) { return __builtin_amdgcn_exp2f(x); }  // v_exp_f32

DEV f4 mfma16(h8 a, h8 b, f4 c) {
  return __builtin_amdgcn_mfma_f32_16x16x32_f16(a, b, c, 0, 0, 0);
}

DEV f16x16 mfma32(h8 a, h8 b, f16x16 c) {
  return __builtin_amdgcn_mfma_f32_32x32x16_f16(a, b, c, 0, 0, 0);
}

// async global->LDS, 16B per lane. LDS dest must be contiguous in lane order.
DEV void g2l16(void* lds, const void* g) {
  __builtin_amdgcn_global_load_lds((gu32*)(uintptr_t)g, (lu32*)(uintptr_t)lds,
                                   16, 0, 0);
}

// pack two f32 -> f16x2 word with round-to-nearest (matches scalar casts)
DEV uint32_t pkrn(float a, float b) {
  h2 t;
  t[0] = (_Float16)a;
  t[1] = (_Float16)b;
  return __builtin_bit_cast(uint32_t, t);
}

// permlane32_swap(x,y): swaps upper half of x with lower half of y.
// returns { [x_lo | y_lo], [x_hi | y_hi] }
DEV u32x2 pl32swap(uint32_t x, uint32_t y) {
  return __builtin_amdgcn_permlane32_swap(x, y, false, false);
}

// ---------------------------------------------------------------------------
// Merged converts. bid < 8192: x fp32 -> f16 (4/thread).
// bid >= 8192: W slice [1024][128] fp32 -> WT [128][1024] f16 (and Wo -> WoT).
__global__ __launch_bounds__(256) void cvt_all_kernel(
    const float* __restrict__ x, _Float16* __restrict__ Xb,
    const float* __restrict__ W, const float* __restrict__ Wo,
    _Float16* __restrict__ WT, _Float16* __restrict__ WoT) {
  __shared__ float st[64][68];
  const int bid = blockIdx.x;
  const int tid = threadIdx.x;
  if (bid < 8192) {
    size_t i = (size_t)(bid * 256 + tid) * 4;
    f4 v = *(const f4*)(x + i);
    h4 o;
    o[0] = (_Float16)v[0];
    o[1] = (_Float16)v[1];
    o[2] = (_Float16)v[2];
    o[3] = (_Float16)v[3];
    *(h4*)(Xb + i) = o;
    return;
  }
  const int idx0 = bid - 8192;
  const int mz = idx0 >> 5;        // 0..24
  const int rem = idx0 & 31;
  const int d0 = (rem & 15) * 64;  // rows (1024)
  const int e0 = (rem >> 4) * 64;  // cols (128)
  const float* src = (mz < 24) ? (W + (size_t)mz * 131072) : Wo;
  _Float16* dst = (mz < 24) ? (WT + (size_t)mz * 131072) : WoT;
#pragma unroll
  for (int r = 0; r < 4; ++r) {
    int idx = r * 256 + tid;
    int dd = idx >> 4, cc = (idx & 15) * 4;
    f4 v = *(const f4*)(src + (size_t)(d0 + dd) * 128 + e0 + cc);
    *(f4*)&st[dd][cc] = v;
  }
  __syncthreads();
#pragma unroll
  for (int r = 0; r < 2; ++r) {
    int idx = r * 256 + tid;
    int ee = idx >> 3, dd = (idx & 7) * 8;
    h8 o;
#pragma unroll
    for (int i = 0; i < 8; ++i) o[i] = (_Float16)st[dd + i][ee];
    *(h8*)(dst + (size_t)(e0 + ee) * 1024 + d0 + dd) = o;
  }
}

// ---------------------------------------------------------------------------
// C[256 x 128] = A[256 x 1024] * BT[128 x 1024]^T, XOR-swizzled LDS.
// 4 waves x (128 M x 64 N) per wave via mfma 32x32x16 (acc[4][2] f16x16).
// Grid (32 m, 24 j), m fastest -> A-tile of each m pinned to one XCD's L2.
// 768 blocks = exactly 3/CU (48 KB LDS, launch_bounds(256,3)).
// QKV epilogue in two 128-row halves through 32 KB swizzled LDS round-trip.
__global__ __launch_bounds__(256, 3) void gemm_qkv_kernel(
    const _Float16* __restrict__ A, const _Float16* __restrict__ BTall,
    _Float16* __restrict__ Qb, _Float16* __restrict__ Kb,
    _Float16* __restrict__ VTb) {
  __shared__ __align__(16) _Float16 sAB[24576];  // sA [0,16384), sB [16384,..)
  const int tid = threadIdx.x;
  const int wave = tid >> 6, lane = tid & 63;
  const int l31 = lane & 31, hi = lane >> 5;
  const int sw = l31 & 7;
  const int m0 = blockIdx.x * 256;
  const int j = blockIdx.y;
  const _Float16* BT = BTall + (size_t)j * (128 * 1024);

  const int wr = (wave >> 1) * 128;  // wave's M offset
  const int wc = (wave & 1) * 64;    // wave's N offset

  f16x16 acc[4][2] = {};  // [mi][ni]: (wr+mi*32 .. +31) x (wc+ni*32 .. +31)

#pragma unroll 1
  for (int kt = 0; kt < 1024; kt += 64) {
    __syncthreads();
#pragma unroll
    for (int r = 0; r < 8; ++r) {  // sA: 256 rows x 8 chunks of 16B
      int idx = r * 256 + tid;
      int row = idx >> 3;
      int jg = (idx & 7) ^ (row & 7);  // source-permute = dest XOR swizzle
      g2l16(&sAB[idx * 8], A + (size_t)(m0 + row) * 1024 + kt + jg * 8);
    }
#pragma unroll
    for (int r = 0; r < 4; ++r) {  // sB: 128 rows x 8 chunks
      int idx = r * 256 + tid;
      int row = idx >> 3;
      int jg = (idx & 7) ^ (row & 7);
      g2l16(&sAB[16384 + idx * 8], BT + (size_t)row * 1024 + kt + jg * 8);
    }
    __syncthreads();
#pragma unroll
    for (int s = 0; s < 4; ++s) {  // 4 x k16 substeps
      int off = ((s * 2 + hi) ^ sw) * 8;
      h8 bf[2];
#pragma unroll
      for (int ni = 0; ni < 2; ++ni)
        bf[ni] = *(const h8*)&sAB[16384 + (wc + ni * 32 + l31) * 64 + off];
#pragma unroll
      for (int mi = 0; mi < 4; ++mi) {
        h8 af = *(const h8*)&sAB[(wr + mi * 32 + l31) * 64 + off];
#pragma unroll
        for (int ni = 0; ni < 2; ++ni)
          acc[mi][ni] = mfma32(af, bf[ni], acc[mi][ni]);
      }
    }
  }

  // C layout (32x32 mfma): col = l31 (within 32-col blk), row = (reg&3) +
  // 8*(reg>>2) + 4*hi  -- validated end-to-end by flash's epilogue.
  const int h = j / 3, s = j - h * 3;
  const int b = m0 >> 11, n0 = m0 & 2047;
  if (s < 2) {
    // Q gets log2(e)/sqrt(128) so flash can run softmax in exp2 domain.
    const float scl = (s == 0) ? 0.12751741032075984f : 1.0f;
    _Float16* dst = (s == 0) ? Qb : Kb;
    size_t rbase = ((size_t)((b * 8 + h) * 2048 + n0)) * 128;
#pragma unroll 1
    for (int half = 0; half < 2; ++half) {
      __syncthreads();  // sAB free (K-loop reads / prev half's reads done)
      if ((wave >> 1) == half) {
#pragma unroll
        for (int mi = 0; mi < 4; ++mi)
#pragma unroll
          for (int reg = 0; reg < 16; ++reg) {
            int rl = mi * 32 + (reg & 3) + 8 * (reg >> 2) + 4 * hi;
#pragma unroll
            for (int ni = 0; ni < 2; ++ni) {
              int c = wc + ni * 32 + l31;
              sAB[rl * 128 + (((c >> 3) ^ (rl & 7)) * 8) + (c & 7)] =
                  (_Float16)(acc[mi][ni][reg] * scl);
            }
          }
      }
      __syncthreads();
      int rr = tid >> 1, seg = tid & 1;
      size_t rb = rbase + (size_t)(half * 128 + rr) * 128;
#pragma unroll
      for (int k = 0; k < 8; ++k) {
        int ch = seg * 8 + k;
        h8 v = *(const h8*)&sAB[rr * 128 + ((ch ^ (rr & 7)) * 8)];
        *(h8*)&dst[rb + ch * 8] = v;
      }
    }
  } else {
    // V: transpose through LDS (swizzled), then coalesced 16B stores
    size_t base = (size_t)(b * 8 + h) * (128 * 2048);
#pragma unroll 1
    for (int half = 0; half < 2; ++half) {
      __syncthreads();
      if ((wave >> 1) == half) {
#pragma unroll
        for (int mi = 0; mi < 4; ++mi)
#pragma unroll
          for (int reg = 0; reg < 16; ++reg) {
            int nl = mi * 32 + (reg & 3) + 8 * (reg >> 2) + 4 * hi;  // local n
            int cc = nl >> 3, ci = nl & 7;
#pragma unroll
            for (int ni = 0; ni < 2; ++ni) {
              int c = wc + ni * 32 + l31;  // d
              sAB[c * 128 + ((cc ^ (c & 7)) * 8) + ci] =
                  (_Float16)acc[mi][ni][reg];
            }
          }
      }
      __syncthreads();
      int c = tid >> 1, seg = tid & 1;
#pragma unroll
      for (int k = 0; k < 8; ++k) {
        int ch = seg * 8 + k;
        h8 v = *(const h8*)&sAB[c * 128 + ((ch ^ (c & 7)) * 8)];
        *(h8*)&VTb[base + (size_t)c * 2048 + n0 + half * 128 + ch * 8] = v;
      }
    }
  }
}

// ---------------------------------------------------------------------------
// Flash attention, 32x32x16 MFMA, fixed-max (M=0) softmax.
// 256 threads = 4 waves x 32 q-rows (Q-tile 128), KV-tile 64.
// Swapped QK^T: S^T = mfma(K, Q) -> lane&31 = q, so each lane owns half a
// P-row; softmax + P->f16 + transpose to PV B-operand run in registers via
// permlane32_swap (no sP LDS round-trip). PV: O^T = mfma(VT, P^T).
// Double-buffered sK/sVT (64 KB), ONE barrier/tile, prefetch distance 1.
__global__ __launch_bounds__(256, 2) void flash_kernel(
    const _Float16* __restrict__ Qb, const _Float16* __restrict__ Kb,
    const _Float16* __restrict__ VTb, _Float16* __restrict__ Oc) {
  __shared__ __align__(16) _Float16 sK[2][64 * 128];   // [kv][d]  2 x 16 KB
  __shared__ __align__(16) _Float16 sVT[2][128 * 64];  // [d][kv]  2 x 16 KB
  const int tid = threadIdx.x, wave = tid >> 6, lane = tid & 63;
  const int l31 = lane & 31, hi = lane >> 5;
  const int sw = l31 & 7;
  const int bh = blockIdx.x, b = bh >> 3, h = bh & 7;
  const int q0 = blockIdx.y * 128;
  const _Float16* Q = Qb + (size_t)bh * (2048 * 128);
  const _Float16* Kp = Kb + (size_t)bh * (2048 * 128);
  const _Float16* VT = VTb + (size_t)bh * (128 * 2048);

  // hoist Q fragments: wave-local q row = l31 (global q0 + wave*32 + l31);
  // B-operand layout: col = lane&31, k-elems = (lane>>5)*8 within each 16.
  h8 qf[8];
#pragma unroll
  for (int c = 0; c < 8; ++c)
    qf[c] = *(const h8*)&Q[(size_t)(q0 + wave * 32 + l31) * 128 + c * 16 +
                           hi * 8];

  f16x16 oacc[4] = {};  // O^T[d][q]: 4 d-tiles of 32
  float lsum = 0.0f;    // my half of the P row-sum (q = l31)

// stage one KV tile (sK 1024 + sVT 1024 16B-chunks, 256 threads -> 4 each)
#define STAGE(buf, kv0)                                                        \
  {                                                                            \
    _Float16* dK = &sK[buf][0];                                                \
    _Float16* dV = &sVT[buf][0];                                               \
    _Pragma("unroll") for (int i = 0; i < 4; ++i) {                            \
      int idx = i * 256 + tid;                                                 \
      int rk = idx >> 4, ck = idx & 15;                                        \
      g2l16(dK + idx * 8,                                                      \
            Kp + (size_t)((kv0) + rk) * 128 + ((ck ^ (rk & 7)) * 8));          \
      int rv = idx >> 3, cv = idx & 7;                                         \
      g2l16(dV + idx * 8,                                                      \
            VT + (size_t)rv * 2048 + (kv0) + ((cv ^ (rv & 7)) * 8));           \
    }                                                                          \
  }

  STAGE(0, 0);
  int cur = 0;
#pragma unroll 1
  for (int t = 0; t < 32; ++t) {
    // barrier: staging of buf[cur] (issued a full tile ago) is drained by the
    // implicit vmcnt(0); also fences last tile's reads of buf[cur^1].
    __syncthreads();
    if (t < 31) STAGE(cur ^ 1, (t + 1) * 64);
    const _Float16* bK = &sK[cur][0];
    const _Float16* bV = &sVT[cur][0];

    // S^T = K * Q^T over d=128 (8 k-steps). s0: kv 0..31, s1: kv 32..63.
    f16x16 s0 = {}, s1 = {};
#pragma unroll
    for (int c = 0; c < 8; ++c) {
      int off = ((c * 2 + hi) ^ sw) * 8;
      h8 a0 = *(const h8*)&bK[l31 * 128 + off];
      h8 a1 = *(const h8*)&bK[(32 + l31) * 128 + off];
      s0 = mfma32(a0, qf[c], s0);
      s1 = mfma32(a1, qf[c], s1);
    }

    // p = exp2(s) (Q pre-scaled); row-sum partial; pack adjacent-kv f16 pairs.
    // reg r of a 32x32 acc holds kv-row (r&3) + 8*(r>>2) + 4*hi.
    // => w[j] holds kv pair { 8*(j>>1) + 4*hi + 2*(j&1), +1 } for q = l31.
    uint32_t w0[8], w1[8];
#pragma unroll
    for (int j = 0; j < 8; ++j) {
      float a0 = fexp2(s0[2 * j]), b0 = fexp2(s0[2 * j + 1]);
      float a1 = fexp2(s1[2 * j]), b1 = fexp2(s1[2 * j + 1]);
      lsum += (a0 + b0) + (a1 + b1);
      w0[j] = pkrn(a0, b0);
      w1[j] = pkrn(a1, b1);
    }

    // Build PV B-frags: chunk c word wi must hold kv = c*16 + hi*8 + 2*wi+{0,1}
    // (q = l31). swap(w[4h+0], w[4h+2]) -> {word0, word2};
    // swap(w[4h+1], w[4h+3]) -> {word1, word3}.  (half h = chunk within s0/s1)
    h8 pf[4];
#pragma unroll
    for (int half = 0; half < 2; ++half) {
      u32x2 r0 = pl32swap(w0[half * 4 + 0], w0[half * 4 + 2]);
      u32x2 r1 = pl32swap(w0[half * 4 + 1], w0[half * 4 + 3]);
      u32x4 tt;
      tt[0] = r0[0];
      tt[1] = r1[0];
      tt[2] = r0[1];
      tt[3] = r1[1];
      pf[half] = __builtin_bit_cast(h8, tt);
      u32x2 r2 = pl32swap(w1[half * 4 + 0], w1[half * 4 + 2]);
      u32x2 r3 = pl32swap(w1[half * 4 + 1], w1[half * 4 + 3]);
      u32x4 uu;
      uu[0] = r2[0];
      uu[1] = r3[0];
      uu[2] = r2[1];
      uu[3] = r3[1];
      pf[2 + half] = __builtin_bit_cast(h8, uu);
    }

    // O^T[d][q] += V^T[d][kv] * P^T[kv][q]  (A = VT rows, B = P rows)
#pragma unroll
    for (int dt = 0; dt < 4; ++dt) {
#pragma unroll
      for (int c = 0; c < 4; ++c) {
        int off = ((c * 2 + hi) ^ sw) * 8;
        h8 vf = *(const h8*)&bV[(dt * 32 + l31) * 64 + off];
        oacc[dt] = mfma32(vf, pf[c], oacc[dt]);
      }
    }
    cur ^= 1;
  }
#undef STAGE

  // full row-sum: lane and lane^32 hold the same q (= l31)
  lsum += __shfl_xor(lsum, 32, 64);
  const float inv = 1.0f / lsum;

  // epilogue: transpose O^T -> O through reused sK (wave-private 8 KB)
  __syncthreads();  // all waves done reading sK/sVT
  _Float16* sO = &sK[0][0] + wave * 4096;  // [32 q][128 d], chunk-XOR swizzle
#pragma unroll
  for (int dt = 0; dt < 4; ++dt)
#pragma unroll
    for (int r = 0; r < 16; ++r) {
      int d = dt * 32 + (r & 3) + 8 * (r >> 2) + 4 * hi;
      sO[l31 * 128 + (d ^ (sw << 3))] = (_Float16)(oacc[dt][r] * inv);
    }
  const int l15 = lane & 15, gq = lane >> 4;
#pragma unroll
  for (int it = 0; it < 8; ++it) {
    int q = it * 4 + gq;  // 4 q-rows x 16 chunks per instruction
    h8 v = *(const h8*)&sO[q * 128 + ((l15 ^ (q & 7)) * 8)];
    int n = q0 + wave * 32 + q;
    *(h8*)&Oc[((size_t)(b * 2048 + n)) * 1024 + h * 128 + l15 * 8] = v;
  }
}

// ---------------------------------------------------------------------------
// out[16 x 128] tiles = Oc[16 x 1024] * WoT[128 x 1024]^T, grid 512 blocks
// = 2 blocks/CU.
__global__ __launch_bounds__(256, 4) void gemm_out_kernel(
    const _Float16* __restrict__ A, const _Float16* __restrict__ BT,
    float* __restrict__ outF) {
  __shared__ __align__(16) _Float16 sA[16 * 64];   // 2 KB
  __shared__ __align__(16) _Float16 sB[128 * 64];  // 16 KB
  const int tid = threadIdx.x, wave = tid >> 6, lane = tid & 63;
  const int g = lane >> 4, l15 = lane & 15, sw = l15 & 7;
  const int m0 = blockIdx.x * 16;
  f4 acc[2] = {};

#pragma unroll 1
  for (int kt = 0; kt < 1024; kt += 64) {
    __syncthreads();
    if (tid < 128) {
      int row = tid >> 3;
      int jg = (tid & 7) ^ (row & 7);
      g2l16(&sA[tid * 8], A + (size_t)(m0 + row) * 1024 + kt + jg * 8);
    }
#pragma unroll
    for (int r = 0; r < 4; ++r) {
      int idx = r * 256 + tid;
      int row = idx >> 3;
      int jg = (idx & 7) ^ (row & 7);
      g2l16(&sB[idx * 8], BT + (size_t)row * 1024 + kt + jg * 8);
    }
    __syncthreads();
#pragma unroll
    for (int ks = 0; ks < 2; ++ks) {
      int off = ((ks * 4 + g) ^ sw) * 8;
      h8 af = *(const h8*)&sA[l15 * 64 + off];
#pragma unroll
      for (int nt = 0; nt < 2; ++nt) {
        h8 bf = *(const h8*)&sB[(wave * 32 + nt * 16 + l15) * 64 + off];
        acc[nt] = mfma16(af, bf, acc[nt]);
      }
    }
  }
#pragma unroll
  for (int rg = 0; rg < 4; ++rg) {
    int m = m0 + g * 4 + rg;
#pragma unroll
    for (int nt = 0; nt < 2; ++nt)
      outF[(size_t)m * 128 + wave * 32 + nt * 16 + l15] = acc[nt][rg];
  }
}

// ---------------------------------------------------------------------------
extern "C" void kernel_launch(void* const* d_in, const int* in_sizes, int n_in,
                              void* d_out, int out_size, void* d_ws,
                              size_t ws_size, hipStream_t stream) {
  const float* x = (const float*)d_in[0];   // [4][2048][1024]
  const float* W = (const float*)d_in[1];   // [8][3][1024][128]
  const float* Wo = (const float*)d_in[2];  // [1024][128]
  float* out = (float*)d_out;               // [4][2048][128]
  char* ws = (char*)d_ws;

  _Float16* Xb = (_Float16*)(ws + 0);
  _Float16* WT = (_Float16*)(ws + 16777216);
  _Float16* WoT = (_Float16*)(ws + 23068672);
  _Float16* Qb = (_Float16*)(ws + 23330816);
  _Float16* Kb = (_Float16*)(ws + 40108032);
  _Float16* VTb = (_Float16*)(ws + 56885248);
  _Float16* Oc = (_Float16*)(ws + 73662464);

  cvt_all_kernel<<<8992, 256, 0, stream>>>(x, Xb, W, Wo, WT, WoT);
  gemm_qkv_kernel<<<dim3(32, 24), 256, 0, stream>>>(Xb, WT, Qb, Kb, VTb);
  flash_kernel<<<dim3(32, 16), 256, 0, stream>>>(Qb, Kb, VTb, Oc);
  gemm_out_kernel<<<512, 256, 0, stream>>>(Oc, WoT, out);
}

// Round 4
// 255.373 us; speedup vs baseline: 1.1491x; 1.1491x over previous
//
#include <hip/hip_runtime.h>
#include <cstdint>

// ============================================================================
// Fused MHA forward, MI355X/gfx950. f16 MFMA pipeline:
//   1. cvt_all: x fp32 -> Xb f16 (blocks < 8192); W,Wo -> WT/WoT transposed f16
//   2. gemm_qkv: QKV = Xb @ WT^T -> Qb,Kb (Q pre-scaled log2e/sqrt(128)),
//               V transposed via LDS -> VTb [bh][d][n]. 256x128 tiles,
//               4 waves x (128x64) per wave, mfma 32x32x16, BK=64, 48 KB LDS,
//               grid (32 m, 24 j) = 768 blocks = 3 per CU over 2 resident
//               slots (launch_bounds(256,2): acc needs 128 AccVGPR + ~84
//               ArchVGPR = ~212 unified regs -> min-waves 3 would spill).
//   3. flash:   32x32x16-MFMA flash, fixed-max (M=0) softmax, SWAPPED QK^T
//               (S^T = mfma(K,Q): lane&31 = q) so softmax + P-transpose run
//               fully in registers (cvt to f16 pairs + permlane32_swap,
//               no sP LDS round-trip). 256-thread blocks (4 waves x 32 q),
//               KV-tile 64, double-buffered sK/sVT (64 KB), ONE barrier/tile.
//               PV computes O^T = mfma(VT, P^T); epilogue transposes O via
//               reused sK LDS -> coalesced Oc. Grid (32 bh, 16 q) = 2/CU.
//   4. gemm_out: out = Oc @ WoT^T, 16x128 tiles, grid 512 = 2 blocks/CU.
// LDS XOR swizzle (16B chunk ^= row&7) everywhere; staging via
// global_load_lds width-16 with source-permuted addresses (dest lane-linear).
// ============================================================================

#define DEV __device__ __forceinline__

typedef _Float16 h8 __attribute__((ext_vector_type(8)));
typedef _Float16 h4 __attribute__((ext_vector_type(4)));
typedef _Float16 h2 __attribute__((ext_vector_type(2)));
typedef float f4 __attribute__((ext_vector_type(4)));
typedef float f16x16 __attribute__((ext_vector_type(16)));
typedef uint32_t u32x4 __attribute__((ext_vector_type(4)));
typedef uint32_t u32x2 __attribute__((ext_vector_type(2)));

typedef __attribute__((address_space(1))) const uint32_t gu32;
typedef __attribute__((address_space(3))) uint32_t lu32;

DEV float fexp2(float x) { return __builtin_amdgcn_exp2f(x); }  // v_exp_f32

DEV f4 mfma16(h8 a, h8 b, f4 c) {
  return __builtin_amdgcn_mfma_f32_16x16x32_f16(a, b, c, 0, 0, 0);
}

DEV f16x16 mfma32(h8 a, h8 b, f16x16 c) {
  return __builtin_amdgcn_mfma_f32_32x32x16_f16(a, b, c, 0, 0, 0);
}

// async global->LDS, 16B per lane. LDS dest must be contiguous in lane order.
DEV void g2l16(void* lds, const void* g) {
  __builtin_amdgcn_global_load_lds((gu32*)(uintptr_t)g, (lu32*)(uintptr_t)lds,
                                   16, 0, 0);
}

// pack two f32 -> f16x2 word with round-to-nearest (matches scalar casts)
DEV uint32_t pkrn(float a, float b) {
  h2 t;
  t[0] = (_Float16)a;
  t[1] = (_Float16)b;
  return __builtin_bit_cast(uint32_t, t);
}

// permlane32_swap(x,y): swaps upper half of x with lower half of y.
// returns { [x_lo | y_lo], [x_hi | y_hi] }
DEV u32x2 pl32swap(uint32_t x, uint32_t y) {
  return __builtin_amdgcn_permlane32_swap(x, y, false, false);
}

// ---------------------------------------------------------------------------
// Merged converts. bid < 8192: x fp32 -> f16 (4/thread).
// bid >= 8192: W slice [1024][128] fp32 -> WT [128][1024] f16 (and Wo -> WoT).
__global__ __launch_bounds__(256) void cvt_all_kernel(
    const float* __restrict__ x, _Float16* __restrict__ Xb,
    const float* __restrict__ W, const float* __restrict__ Wo,
    _Float16* __restrict__ WT, _Float16* __restrict__ WoT) {
  __shared__ float st[64][68];
  const int bid = blockIdx.x;
  const int tid = threadIdx.x;
  if (bid < 8192) {
    size_t i = (size_t)(bid * 256 + tid) * 4;
    f4 v = *(const f4*)(x + i);
    h4 o;
    o[0] = (_Float16)v[0];
    o[1] = (_Float16)v[1];
    o[2] = (_Float16)v[2];
    o[3] = (_Float16)v[3];
    *(h4*)(Xb + i) = o;
    return;
  }
  const int idx0 = bid - 8192;
  const int mz = idx0 >> 5;        // 0..24
  const int rem = idx0 & 31;
  const int d0 = (rem & 15) * 64;  // rows (1024)
  const int e0 = (rem >> 4) * 64;  // cols (128)
  const float* src = (mz < 24) ? (W + (size_t)mz * 131072) : Wo;
  _Float16* dst = (mz < 24) ? (WT + (size_t)mz * 131072) : WoT;
#pragma unroll
  for (int r = 0; r < 4; ++r) {
    int idx = r * 256 + tid;
    int dd = idx >> 4, cc = (idx & 15) * 4;
    f4 v = *(const f4*)(src + (size_t)(d0 + dd) * 128 + e0 + cc);
    *(f4*)&st[dd][cc] = v;
  }
  __syncthreads();
#pragma unroll
  for (int r = 0; r < 2; ++r) {
    int idx = r * 256 + tid;
    int ee = idx >> 3, dd = (idx & 7) * 8;
    h8 o;
#pragma unroll
    for (int i = 0; i < 8; ++i) o[i] = (_Float16)st[dd + i][ee];
    *(h8*)(dst + (size_t)(e0 + ee) * 1024 + d0 + dd) = o;
  }
}

// ---------------------------------------------------------------------------
// C[256 x 128] = A[256 x 1024] * BT[128 x 1024]^T, XOR-swizzled LDS.
// 4 waves x (128 M x 64 N) per wave via mfma 32x32x16 (acc[4][2] f16x16).
// Grid (32 m, 24 j), m fastest -> A-tile of each m pinned to one XCD's L2.
// launch_bounds(256,2): ~212 unified VGPRs (128 acc + ~84 arch) needs the
// 256-reg cap; min-waves 3 (170-reg cap) spills acc to scratch (R3: +62 MB
// WRITE_SIZE, MfmaUtil 16%). 768 blocks = 3 per CU over 2 resident slots.
// QKV epilogue in two 128-row halves through 32 KB swizzled LDS round-trip.
__global__ __launch_bounds__(256, 2) void gemm_qkv_kernel(
    const _Float16* __restrict__ A, const _Float16* __restrict__ BTall,
    _Float16* __restrict__ Qb, _Float16* __restrict__ Kb,
    _Float16* __restrict__ VTb) {
  __shared__ __align__(16) _Float16 sAB[24576];  // sA [0,16384), sB [16384,..)
  const int tid = threadIdx.x;
  const int wave = tid >> 6, lane = tid & 63;
  const int l31 = lane & 31, hi = lane >> 5;
  const int sw = l31 & 7;
  const int m0 = blockIdx.x * 256;
  const int j = blockIdx.y;
  const _Float16* BT = BTall + (size_t)j * (128 * 1024);

  const int wr = (wave >> 1) * 128;  // wave's M offset
  const int wc = (wave & 1) * 64;    // wave's N offset

  f16x16 acc[4][2] = {};  // [mi][ni]: (wr+mi*32 .. +31) x (wc+ni*32 .. +31)

#pragma unroll 1
  for (int kt = 0; kt < 1024; kt += 64) {
    __syncthreads();
#pragma unroll
    for (int r = 0; r < 8; ++r) {  // sA: 256 rows x 8 chunks of 16B
      int idx = r * 256 + tid;
      int row = idx >> 3;
      int jg = (idx & 7) ^ (row & 7);  // source-permute = dest XOR swizzle
      g2l16(&sAB[idx * 8], A + (size_t)(m0 + row) * 1024 + kt + jg * 8);
    }
#pragma unroll
    for (int r = 0; r < 4; ++r) {  // sB: 128 rows x 8 chunks
      int idx = r * 256 + tid;
      int row = idx >> 3;
      int jg = (idx & 7) ^ (row & 7);
      g2l16(&sAB[16384 + idx * 8], BT + (size_t)row * 1024 + kt + jg * 8);
    }
    __syncthreads();
#pragma unroll
    for (int s = 0; s < 4; ++s) {  // 4 x k16 substeps
      int off = ((s * 2 + hi) ^ sw) * 8;
      h8 bf[2];
#pragma unroll
      for (int ni = 0; ni < 2; ++ni)
        bf[ni] = *(const h8*)&sAB[16384 + (wc + ni * 32 + l31) * 64 + off];
#pragma unroll
      for (int mi = 0; mi < 4; ++mi) {
        h8 af = *(const h8*)&sAB[(wr + mi * 32 + l31) * 64 + off];
#pragma unroll
        for (int ni = 0; ni < 2; ++ni)
          acc[mi][ni] = mfma32(af, bf[ni], acc[mi][ni]);
      }
    }
  }

  // C layout (32x32 mfma): col = l31 (within 32-col blk), row = (reg&3) +
  // 8*(reg>>2) + 4*hi  -- validated end-to-end by flash's epilogue.
  const int h = j / 3, s = j - h * 3;
  const int b = m0 >> 11, n0 = m0 & 2047;
  if (s < 2) {
    // Q gets log2(e)/sqrt(128) so flash can run softmax in exp2 domain.
    const float scl = (s == 0) ? 0.12751741032075984f : 1.0f;
    _Float16* dst = (s == 0) ? Qb : Kb;
    size_t rbase = ((size_t)((b * 8 + h) * 2048 + n0)) * 128;
#pragma unroll 1
    for (int half = 0; half < 2; ++half) {
      __syncthreads();  // sAB free (K-loop reads / prev half's reads done)
      if ((wave >> 1) == half) {
#pragma unroll
        for (int mi = 0; mi < 4; ++mi)
#pragma unroll
          for (int reg = 0; reg < 16; ++reg) {
            int rl = mi * 32 + (reg & 3) + 8 * (reg >> 2) + 4 * hi;
#pragma unroll
            for (int ni = 0; ni < 2; ++ni) {
              int c = wc + ni * 32 + l31;
              sAB[rl * 128 + (((c >> 3) ^ (rl & 7)) * 8) + (c & 7)] =
                  (_Float16)(acc[mi][ni][reg] * scl);
            }
          }
      }
      __syncthreads();
      int rr = tid >> 1, seg = tid & 1;
      size_t rb = rbase + (size_t)(half * 128 + rr) * 128;
#pragma unroll
      for (int k = 0; k < 8; ++k) {
        int ch = seg * 8 + k;
        h8 v = *(const h8*)&sAB[rr * 128 + ((ch ^ (rr & 7)) * 8)];
        *(h8*)&dst[rb + ch * 8] = v;
      }
    }
  } else {
    // V: transpose through LDS (swizzled), then coalesced 16B stores
    size_t base = (size_t)(b * 8 + h) * (128 * 2048);
#pragma unroll 1
    for (int half = 0; half < 2; ++half) {
      __syncthreads();
      if ((wave >> 1) == half) {
#pragma unroll
        for (int mi = 0; mi < 4; ++mi)
#pragma unroll
          for (int reg = 0; reg < 16; ++reg) {
            int nl = mi * 32 + (reg & 3) + 8 * (reg >> 2) + 4 * hi;  // local n
            int cc = nl >> 3, ci = nl & 7;
#pragma unroll
            for (int ni = 0; ni < 2; ++ni) {
              int c = wc + ni * 32 + l31;  // d
              sAB[c * 128 + ((cc ^ (c & 7)) * 8) + ci] =
                  (_Float16)acc[mi][ni][reg];
            }
          }
      }
      __syncthreads();
      int c = tid >> 1, seg = tid & 1;
#pragma unroll
      for (int k = 0; k < 8; ++k) {
        int ch = seg * 8 + k;
        h8 v = *(const h8*)&sAB[c * 128 + ((ch ^ (c & 7)) * 8)];
        *(h8*)&VTb[base + (size_t)c * 2048 + n0 + half * 128 + ch * 8] = v;
      }
    }
  }
}

// ---------------------------------------------------------------------------
// Flash attention, 32x32x16 MFMA, fixed-max (M=0) softmax.
// 256 threads = 4 waves x 32 q-rows (Q-tile 128), KV-tile 64.
// Swapped QK^T: S^T = mfma(K, Q) -> lane&31 = q, so each lane owns half a
// P-row; softmax + P->f16 + transpose to PV B-operand run in registers via
// permlane32_swap (no sP LDS round-trip). PV: O^T = mfma(VT, P^T).
// Double-buffered sK/sVT (64 KB), ONE barrier/tile, prefetch distance 1.
__global__ __launch_bounds__(256, 2) void flash_kernel(
    const _Float16* __restrict__ Qb, const _Float16* __restrict__ Kb,
    const _Float16* __restrict__ VTb, _Float16* __restrict__ Oc) {
  __shared__ __align__(16) _Float16 sK[2][64 * 128];   // [kv][d]  2 x 16 KB
  __shared__ __align__(16) _Float16 sVT[2][128 * 64];  // [d][kv]  2 x 16 KB
  const int tid = threadIdx.x, wave = tid >> 6, lane = tid & 63;
  const int l31 = lane & 31, hi = lane >> 5;
  const int sw = l31 & 7;
  const int bh = blockIdx.x, b = bh >> 3, h = bh & 7;
  const int q0 = blockIdx.y * 128;
  const _Float16* Q = Qb + (size_t)bh * (2048 * 128);
  const _Float16* Kp = Kb + (size_t)bh * (2048 * 128);
  const _Float16* VT = VTb + (size_t)bh * (128 * 2048);

  // hoist Q fragments: wave-local q row = l31 (global q0 + wave*32 + l31);
  // B-operand layout: col = lane&31, k-elems = (lane>>5)*8 within each 16.
  h8 qf[8];
#pragma unroll
  for (int c = 0; c < 8; ++c)
    qf[c] = *(const h8*)&Q[(size_t)(q0 + wave * 32 + l31) * 128 + c * 16 +
                           hi * 8];

  f16x16 oacc[4] = {};  // O^T[d][q]: 4 d-tiles of 32
  float lsum = 0.0f;    // my half of the P row-sum (q = l31)

// stage one KV tile (sK 1024 + sVT 1024 16B-chunks, 256 threads -> 4 each)
#define STAGE(buf, kv0)                                                        \
  {                                                                            \
    _Float16* dK = &sK[buf][0];                                                \
    _Float16* dV = &sVT[buf][0];                                               \
    _Pragma("unroll") for (int i = 0; i < 4; ++i) {                            \
      int idx = i * 256 + tid;                                                 \
      int rk = idx >> 4, ck = idx & 15;                                        \
      g2l16(dK + idx * 8,                                                      \
            Kp + (size_t)((kv0) + rk) * 128 + ((ck ^ (rk & 7)) * 8));          \
      int rv = idx >> 3, cv = idx & 7;                                         \
      g2l16(dV + idx * 8,                                                      \
            VT + (size_t)rv * 2048 + (kv0) + ((cv ^ (rv & 7)) * 8));           \
    }                                                                          \
  }

  STAGE(0, 0);
  int cur = 0;
#pragma unroll 1
  for (int t = 0; t < 32; ++t) {
    // barrier: staging of buf[cur] (issued a full tile ago) is drained by the
    // implicit vmcnt(0); also fences last tile's reads of buf[cur^1].
    __syncthreads();
    if (t < 31) STAGE(cur ^ 1, (t + 1) * 64);
    const _Float16* bK = &sK[cur][0];
    const _Float16* bV = &sVT[cur][0];

    // S^T = K * Q^T over d=128 (8 k-steps). s0: kv 0..31, s1: kv 32..63.
    f16x16 s0 = {}, s1 = {};
#pragma unroll
    for (int c = 0; c < 8; ++c) {
      int off = ((c * 2 + hi) ^ sw) * 8;
      h8 a0 = *(const h8*)&bK[l31 * 128 + off];
      h8 a1 = *(const h8*)&bK[(32 + l31) * 128 + off];
      s0 = mfma32(a0, qf[c], s0);
      s1 = mfma32(a1, qf[c], s1);
    }

    // p = exp2(s) (Q pre-scaled); row-sum partial; pack adjacent-kv f16 pairs.
    // reg r of a 32x32 acc holds kv-row (r&3) + 8*(r>>2) + 4*hi.
    // => w[j] holds kv pair { 8*(j>>1) + 4*hi + 2*(j&1), +1 } for q = l31.
    uint32_t w0[8], w1[8];
#pragma unroll
    for (int j = 0; j < 8; ++j) {
      float a0 = fexp2(s0[2 * j]), b0 = fexp2(s0[2 * j + 1]);
      float a1 = fexp2(s1[2 * j]), b1 = fexp2(s1[2 * j + 1]);
      lsum += (a0 + b0) + (a1 + b1);
      w0[j] = pkrn(a0, b0);
      w1[j] = pkrn(a1, b1);
    }

    // Build PV B-frags: chunk c word wi must hold kv = c*16 + hi*8 + 2*wi+{0,1}
    // (q = l31). swap(w[4h+0], w[4h+2]) -> {word0, word2};
    // swap(w[4h+1], w[4h+3]) -> {word1, word3}.  (half h = chunk within s0/s1)
    h8 pf[4];
#pragma unroll
    for (int half = 0; half < 2; ++half) {
      u32x2 r0 = pl32swap(w0[half * 4 + 0], w0[half * 4 + 2]);
      u32x2 r1 = pl32swap(w0[half * 4 + 1], w0[half * 4 + 3]);
      u32x4 tt;
      tt[0] = r0[0];
      tt[1] = r1[0];
      tt[2] = r0[1];
      tt[3] = r1[1];
      pf[half] = __builtin_bit_cast(h8, tt);
      u32x2 r2 = pl32swap(w1[half * 4 + 0], w1[half * 4 + 2]);
      u32x2 r3 = pl32swap(w1[half * 4 + 1], w1[half * 4 + 3]);
      u32x4 uu;
      uu[0] = r2[0];
      uu[1] = r3[0];
      uu[2] = r2[1];
      uu[3] = r3[1];
      pf[2 + half] = __builtin_bit_cast(h8, uu);
    }

    // O^T[d][q] += V^T[d][kv] * P^T[kv][q]  (A = VT rows, B = P rows)
#pragma unroll
    for (int dt = 0; dt < 4; ++dt) {
#pragma unroll
      for (int c = 0; c < 4; ++c) {
        int off = ((c * 2 + hi) ^ sw) * 8;
        h8 vf = *(const h8*)&bV[(dt * 32 + l31) * 64 + off];
        oacc[dt] = mfma32(vf, pf[c], oacc[dt]);
      }
    }
    cur ^= 1;
  }
#undef STAGE

  // full row-sum: lane and lane^32 hold the same q (= l31)
  lsum += __shfl_xor(lsum, 32, 64);
  const float inv = 1.0f / lsum;

  // epilogue: transpose O^T -> O through reused sK (wave-private 8 KB)
  __syncthreads();  // all waves done reading sK/sVT
  _Float16* sO = &sK[0][0] + wave * 4096;  // [32 q][128 d], chunk-XOR swizzle
#pragma unroll
  for (int dt = 0; dt < 4; ++dt)
#pragma unroll
    for (int r = 0; r < 16; ++r) {
      int d = dt * 32 + (r & 3) + 8 * (r >> 2) + 4 * hi;
      sO[l31 * 128 + (d ^ (sw << 3))] = (_Float16)(oacc[dt][r] * inv);
    }
  const int l15 = lane & 15, gq = lane >> 4;
#pragma unroll
  for (int it = 0; it < 8; ++it) {
    int q = it * 4 + gq;  // 4 q-rows x 16 chunks per instruction
    h8 v = *(const h8*)&sO[q * 128 + ((l15 ^ (q & 7)) * 8)];
    int n = q0 + wave * 32 + q;
    *(h8*)&Oc[((size_t)(b * 2048 + n)) * 1024 + h * 128 + l15 * 8] = v;
  }
}

// ---------------------------------------------------------------------------
// out[16 x 128] tiles = Oc[16 x 1024] * WoT[128 x 1024]^T, grid 512 blocks
// = 2 blocks/CU.
__global__ __launch_bounds__(256, 4) void gemm_out_kernel(
    const _Float16* __restrict__ A, const _Float16* __restrict__ BT,
    float* __restrict__ outF) {
  __shared__ __align__(16) _Float16 sA[16 * 64];   // 2 KB
  __shared__ __align__(16) _Float16 sB[128 * 64];  // 16 KB
  const int tid = threadIdx.x, wave = tid >> 6, lane = tid & 63;
  const int g = lane >> 4, l15 = lane & 15, sw = l15 & 7;
  const int m0 = blockIdx.x * 16;
  f4 acc[2] = {};

#pragma unroll 1
  for (int kt = 0; kt < 1024; kt += 64) {
    __syncthreads();
    if (tid < 128) {
      int row = tid >> 3;
      int jg = (tid & 7) ^ (row & 7);
      g2l16(&sA[tid * 8], A + (size_t)(m0 + row) * 1024 + kt + jg * 8);
    }
#pragma unroll
    for (int r = 0; r < 4; ++r) {
      int idx = r * 256 + tid;
      int row = idx >> 3;
      int jg = (idx & 7) ^ (row & 7);
      g2l16(&sB[idx * 8], BT + (size_t)row * 1024 + kt + jg * 8);
    }
    __syncthreads();
#pragma unroll
    for (int ks = 0; ks < 2; ++ks) {
      int off = ((ks * 4 + g) ^ sw) * 8;
      h8 af = *(const h8*)&sA[l15 * 64 + off];
#pragma unroll
      for (int nt = 0; nt < 2; ++nt) {
        h8 bf = *(const h8*)&sB[(wave * 32 + nt * 16 + l15) * 64 + off];
        acc[nt] = mfma16(af, bf, acc[nt]);
      }
    }
  }
#pragma unroll
  for (int rg = 0; rg < 4; ++rg) {
    int m = m0 + g * 4 + rg;
#pragma unroll
    for (int nt = 0; nt < 2; ++nt)
      outF[(size_t)m * 128 + wave * 32 + nt * 16 + l15] = acc[nt][rg];
  }
}

// ---------------------------------------------------------------------------
extern "C" void kernel_launch(void* const* d_in, const int* in_sizes, int n_in,
                              void* d_out, int out_size, void* d_ws,
                              size_t ws_size, hipStream_t stream) {
  const float* x = (const float*)d_in[0];   // [4][2048][1024]
  const float* W = (const float*)d_in[1];   // [8][3][1024][128]
  const float* Wo = (const float*)d_in[2];  // [1024][128]
  float* out = (float*)d_out;               // [4][2048][128]
  char* ws = (char*)d_ws;

  _Float16* Xb = (_Float16*)(ws + 0);
  _Float16* WT = (_Float16*)(ws + 16777216);
  _Float16* WoT = (_Float16*)(ws + 23068672);
  _Float16* Qb = (_Float16*)(ws + 23330816);
  _Float16* Kb = (_Float16*)(ws + 40108032);
  _Float16* VTb = (_Float16*)(ws + 56885248);
  _Float16* Oc = (_Float16*)(ws + 73662464);

  cvt_all_kernel<<<8992, 256, 0, stream>>>(x, Xb, W, Wo, WT, WoT);
  gemm_qkv_kernel<<<dim3(32, 24), 256, 0, stream>>>(Xb, WT, Qb, Kb, VTb);
  flash_kernel<<<dim3(32, 16), 256, 0, stream>>>(Qb, Kb, VTb, Oc);
  gemm_out_kernel<<<512, 256, 0, stream>>>(Oc, WoT, out);
}

// Round 5
// 228.321 us; speedup vs baseline: 1.2853x; 1.1185x over previous
//
#include <hip/hip_runtime.h>
#include <cstdint>

// ============================================================================
// Fused MHA forward, MI355X/gfx950. f16 MFMA pipeline:
//   1. cvt_all: x fp32 -> Xb f16 (blocks < 8192); W,Wo -> WT/WoT transposed f16
//   2. gemm_qkv: QKV = Xb @ WT^T -> Qb,Kb (Q pre-scaled log2e/sqrt(128)),
//               V transposed via LDS -> VTb [bh][d][n]. 128x128 tiles,
//               4 waves x (64x64) via mfma16, BK=64, DOUBLE-BUFFERED LDS
//               (64 KB) with ONE barrier per K-step (flash-style: stage next
//               tile right after the barrier, before compute; next barrier's
//               vmcnt(0) drain waits on loads issued a compute-phase earlier
//               -> free). Grid (64 m, 24 j) = 1536 = exactly 3 waves of
//               2 blocks/CU -> no tail. m fastest -> A-tiles pinned per-XCD.
//   3. flash:   32x32x16-MFMA flash, fixed-max (M=0) softmax, SWAPPED QK^T
//               (S^T = mfma(K,Q): lane&31 = q) so softmax + P-transpose run
//               fully in registers (cvt to f16 pairs + permlane32_swap,
//               no sP LDS round-trip). 256-thread blocks (4 waves x 32 q),
//               KV-tile 64, double-buffered sK/sVT (64 KB), ONE barrier/tile.
//               PV computes O^T = mfma(VT, P^T); epilogue transposes O via
//               reused sK LDS -> coalesced Oc. Grid (32 bh, 16 q) = 2/CU.
//   4. gemm_out: out = Oc @ WoT^T, 16x128 tiles, BK=128, same dbuf
//               single-barrier protocol (72 KB LDS), grid 512 = 2/CU exact.
// LDS XOR swizzle (16B chunk ^= row&7) everywhere; staging via
// global_load_lds width-16 with source-permuted addresses (dest lane-linear).
// ============================================================================

#define DEV __device__ __forceinline__

typedef _Float16 h8 __attribute__((ext_vector_type(8)));
typedef _Float16 h4 __attribute__((ext_vector_type(4)));
typedef _Float16 h2 __attribute__((ext_vector_type(2)));
typedef float f4 __attribute__((ext_vector_type(4)));
typedef float f16x16 __attribute__((ext_vector_type(16)));
typedef uint32_t u32x4 __attribute__((ext_vector_type(4)));
typedef uint32_t u32x2 __attribute__((ext_vector_type(2)));

typedef __attribute__((address_space(1))) const uint32_t gu32;
typedef __attribute__((address_space(3))) uint32_t lu32;

DEV float fexp2(float x) { return __builtin_amdgcn_exp2f(x); }  // v_exp_f32

DEV f4 mfma16(h8 a, h8 b, f4 c) {
  return __builtin_amdgcn_mfma_f32_16x16x32_f16(a, b, c, 0, 0, 0);
}

DEV f16x16 mfma32(h8 a, h8 b, f16x16 c) {
  return __builtin_amdgcn_mfma_f32_32x32x16_f16(a, b, c, 0, 0, 0);
}

// async global->LDS, 16B per lane. LDS dest must be contiguous in lane order.
DEV void g2l16(void* lds, const void* g) {
  __builtin_amdgcn_global_load_lds((gu32*)(uintptr_t)g, (lu32*)(uintptr_t)lds,
                                   16, 0, 0);
}

// pack two f32 -> f16x2 word with round-to-nearest (matches scalar casts)
DEV uint32_t pkrn(float a, float b) {
  h2 t;
  t[0] = (_Float16)a;
  t[1] = (_Float16)b;
  return __builtin_bit_cast(uint32_t, t);
}

// permlane32_swap(x,y): swaps upper half of x with lower half of y.
// returns { [x_lo | y_lo], [x_hi | y_hi] }
DEV u32x2 pl32swap(uint32_t x, uint32_t y) {
  return __builtin_amdgcn_permlane32_swap(x, y, false, false);
}

// ---------------------------------------------------------------------------
// Merged converts. bid < 8192: x fp32 -> f16 (4/thread).
// bid >= 8192: W slice [1024][128] fp32 -> WT [128][1024] f16 (and Wo -> WoT).
__global__ __launch_bounds__(256) void cvt_all_kernel(
    const float* __restrict__ x, _Float16* __restrict__ Xb,
    const float* __restrict__ W, const float* __restrict__ Wo,
    _Float16* __restrict__ WT, _Float16* __restrict__ WoT) {
  __shared__ float st[64][68];
  const int bid = blockIdx.x;
  const int tid = threadIdx.x;
  if (bid < 8192) {
    size_t i = (size_t)(bid * 256 + tid) * 4;
    f4 v = *(const f4*)(x + i);
    h4 o;
    o[0] = (_Float16)v[0];
    o[1] = (_Float16)v[1];
    o[2] = (_Float16)v[2];
    o[3] = (_Float16)v[3];
    *(h4*)(Xb + i) = o;
    return;
  }
  const int idx0 = bid - 8192;
  const int mz = idx0 >> 5;        // 0..24
  const int rem = idx0 & 31;
  const int d0 = (rem & 15) * 64;  // rows (1024)
  const int e0 = (rem >> 4) * 64;  // cols (128)
  const float* src = (mz < 24) ? (W + (size_t)mz * 131072) : Wo;
  _Float16* dst = (mz < 24) ? (WT + (size_t)mz * 131072) : WoT;
#pragma unroll
  for (int r = 0; r < 4; ++r) {
    int idx = r * 256 + tid;
    int dd = idx >> 4, cc = (idx & 15) * 4;
    f4 v = *(const f4*)(src + (size_t)(d0 + dd) * 128 + e0 + cc);
    *(f4*)&st[dd][cc] = v;
  }
  __syncthreads();
#pragma unroll
  for (int r = 0; r < 2; ++r) {
    int idx = r * 256 + tid;
    int ee = idx >> 3, dd = (idx & 7) * 8;
    h8 o;
#pragma unroll
    for (int i = 0; i < 8; ++i) o[i] = (_Float16)st[dd + i][ee];
    *(h8*)(dst + (size_t)(e0 + ee) * 1024 + d0 + dd) = o;
  }
}

// ---------------------------------------------------------------------------
// C[128 x 128] = A[128 x 1024] * BT[128 x 1024]^T, XOR-swizzled LDS.
// 4 waves x (64 M x 64 N) per wave via mfma16 (acc[4][4] f4).
// DOUBLE-BUFFERED staging (2 x 32 KB), ONE barrier per K-step: stage buf^1
// right after the barrier, compute buf; next barrier's vmcnt(0) waits on
// loads issued a full compute-phase earlier (protocol verified in flash).
// Grid (64 m, 24 j) = 1536 blocks = exactly 3 waves of 2/CU -> no tail.
// QKV epilogue through 32 KB swizzled LDS round-trip (reuses buf0 region).
__global__ __launch_bounds__(256, 2) void gemm_qkv_kernel(
    const _Float16* __restrict__ A, const _Float16* __restrict__ BTall,
    _Float16* __restrict__ Qb, _Float16* __restrict__ Kb,
    _Float16* __restrict__ VTb) {
  __shared__ __align__(16) _Float16 sAB[2][16384];  // per buf: A [0,8K) B [8K,16K)
  const int tid = threadIdx.x;
  const int wave = tid >> 6, lane = tid & 63;
  const int g = lane >> 4, l15 = lane & 15;
  const int sw = l15 & 7;
  const int m0 = blockIdx.x * 128;
  const int j = blockIdx.y;
  const _Float16* BT = BTall + (size_t)j * (128 * 1024);

  f4 acc[4][4] = {};
  const int ar = (wave >> 1) * 64 + l15;
  const int br = (wave & 1) * 64 + l15;

// stage one K-step tile: sA 128x8 + sB 128x8 16B-chunks (4+4 per thread)
#define QSTAGE(buf, kt)                                                        \
  {                                                                            \
    _Float16* dA = &sAB[buf][0];                                               \
    _Float16* dB = &sAB[buf][8192];                                            \
    _Pragma("unroll") for (int i = 0; i < 4; ++i) {                            \
      int idx = i * 256 + tid;                                                 \
      int row = idx >> 3;                                                      \
      int jg = (idx & 7) ^ (row & 7); /* source-permute = dest XOR swizzle */  \
      g2l16(dA + idx * 8, A + (size_t)(m0 + row) * 1024 + (kt) + jg * 8);      \
      g2l16(dB + idx * 8, BT + (size_t)row * 1024 + (kt) + jg * 8);            \
    }                                                                          \
  }

  QSTAGE(0, 0);
  int cur = 0;
#pragma unroll 1
  for (int t = 0; t < 16; ++t) {
    // barrier: drains staging of buf[cur] (issued a compute-phase ago) via
    // implicit vmcnt(0); also fences prev step's reads of buf[cur^1].
    __syncthreads();
    if (t < 15) QSTAGE(cur ^ 1, (t + 1) * 64);
    const _Float16* bA = &sAB[cur][0];
    const _Float16* bB = &sAB[cur][8192];
#pragma unroll
    for (int ks = 0; ks < 2; ++ks) {
      int off = ((ks * 4 + g) ^ sw) * 8;
      h8 af[4], bf[4];
#pragma unroll
      for (int mt = 0; mt < 4; ++mt)
        af[mt] = *(const h8*)&bA[(ar + mt * 16) * 64 + off];
#pragma unroll
      for (int nt = 0; nt < 4; ++nt)
        bf[nt] = *(const h8*)&bB[(br + nt * 16) * 64 + off];
#pragma unroll
      for (int mt = 0; mt < 4; ++mt)
#pragma unroll
        for (int nt = 0; nt < 4; ++nt)
          acc[mt][nt] = mfma16(af[mt], bf[nt], acc[mt][nt]);
    }
    cur ^= 1;
  }
#undef QSTAGE

  _Float16* sE = &sAB[0][0];  // 32 KB epilogue scratch ([128][128] swizzled)
  const int wr = (wave >> 1) * 64, wc = (wave & 1) * 64;
  const int h = j / 3, s = j - h * 3;
  if (s < 2) {
    // Q gets log2(e)/sqrt(128) so flash can run softmax in exp2 domain.
    const float scl = (s == 0) ? 0.12751741032075984f : 1.0f;
    _Float16* dst = (s == 0) ? Qb : Kb;
    __syncthreads();  // all waves done with K-loop LDS reads
#pragma unroll
    for (int mt = 0; mt < 4; ++mt)
#pragma unroll
      for (int rg = 0; rg < 4; ++rg) {
        int rl = wr + mt * 16 + g * 4 + rg;  // local row
#pragma unroll
        for (int nt = 0; nt < 4; ++nt) {
          int c = wc + nt * 16 + l15;  // local col
          sE[rl * 128 + (((c >> 3) ^ (rl & 7)) * 8) + (c & 7)] =
              (_Float16)(acc[mt][nt][rg] * scl);
        }
      }
    __syncthreads();
    int rr = tid >> 1, seg = tid & 1;
    int m = m0 + rr, b = m >> 11, n = m & 2047;
    size_t rb = ((size_t)((b * 8 + h) * 2048 + n)) * 128;
#pragma unroll
    for (int k = 0; k < 8; ++k) {
      int ch = seg * 8 + k;
      h8 v = *(const h8*)&sE[rr * 128 + ((ch ^ (rr & 7)) * 8)];
      *(h8*)&dst[rb + ch * 8] = v;
    }
  } else {
    // V: transpose through LDS (swizzled), then coalesced 16B stores
    __syncthreads();
    const int b = m0 >> 11, n0 = m0 & 2047;
    size_t base = (size_t)(b * 8 + h) * (128 * 2048);
#pragma unroll
    for (int mt = 0; mt < 4; ++mt)
#pragma unroll
      for (int rg = 0; rg < 4; ++rg) {
        int nl = wr + mt * 16 + g * 4 + rg;  // local n
        int cc = (nl >> 3), ci = nl & 7;
#pragma unroll
        for (int nt = 0; nt < 4; ++nt) {
          int c = wc + nt * 16 + l15;  // d
          sE[c * 128 + ((cc ^ (c & 7)) * 8) + ci] = (_Float16)acc[mt][nt][rg];
        }
      }
    __syncthreads();
    int c = tid >> 1, seg = tid & 1;
#pragma unroll
    for (int k = 0; k < 8; ++k) {
      int ch = seg * 8 + k;
      h8 v = *(const h8*)&sE[c * 128 + ((ch ^ (c & 7)) * 8)];
      *(h8*)&VTb[base + (size_t)c * 2048 + n0 + ch * 8] = v;
    }
  }
}

// ---------------------------------------------------------------------------
// Flash attention, 32x32x16 MFMA, fixed-max (M=0) softmax.
// 256 threads = 4 waves x 32 q-rows (Q-tile 128), KV-tile 64.
// Swapped QK^T: S^T = mfma(K, Q) -> lane&31 = q, so each lane owns half a
// P-row; softmax + P->f16 + transpose to PV B-operand run in registers via
// permlane32_swap (no sP LDS round-trip). PV: O^T = mfma(VT, P^T).
// Double-buffered sK/sVT (64 KB), ONE barrier/tile, prefetch distance 1.
__global__ __launch_bounds__(256, 2) void flash_kernel(
    const _Float16* __restrict__ Qb, const _Float16* __restrict__ Kb,
    const _Float16* __restrict__ VTb, _Float16* __restrict__ Oc) {
  __shared__ __align__(16) _Float16 sK[2][64 * 128];   // [kv][d]  2 x 16 KB
  __shared__ __align__(16) _Float16 sVT[2][128 * 64];  // [d][kv]  2 x 16 KB
  const int tid = threadIdx.x, wave = tid >> 6, lane = tid & 63;
  const int l31 = lane & 31, hi = lane >> 5;
  const int sw = l31 & 7;
  const int bh = blockIdx.x, b = bh >> 3, h = bh & 7;
  const int q0 = blockIdx.y * 128;
  const _Float16* Q = Qb + (size_t)bh * (2048 * 128);
  const _Float16* Kp = Kb + (size_t)bh * (2048 * 128);
  const _Float16* VT = VTb + (size_t)bh * (128 * 2048);

  // hoist Q fragments: wave-local q row = l31 (global q0 + wave*32 + l31);
  // B-operand layout: col = lane&31, k-elems = (lane>>5)*8 within each 16.
  h8 qf[8];
#pragma unroll
  for (int c = 0; c < 8; ++c)
    qf[c] = *(const h8*)&Q[(size_t)(q0 + wave * 32 + l31) * 128 + c * 16 +
                           hi * 8];

  f16x16 oacc[4] = {};  // O^T[d][q]: 4 d-tiles of 32
  float lsum = 0.0f;    // my half of the P row-sum (q = l31)

// stage one KV tile (sK 1024 + sVT 1024 16B-chunks, 256 threads -> 4 each)
#define STAGE(buf, kv0)                                                        \
  {                                                                            \
    _Float16* dK = &sK[buf][0];                                                \
    _Float16* dV = &sVT[buf][0];                                               \
    _Pragma("unroll") for (int i = 0; i < 4; ++i) {                            \
      int idx = i * 256 + tid;                                                 \
      int rk = idx >> 4, ck = idx & 15;                                        \
      g2l16(dK + idx * 8,                                                      \
            Kp + (size_t)((kv0) + rk) * 128 + ((ck ^ (rk & 7)) * 8));          \
      int rv = idx >> 3, cv = idx & 7;                                         \
      g2l16(dV + idx * 8,                                                      \
            VT + (size_t)rv * 2048 + (kv0) + ((cv ^ (rv & 7)) * 8));           \
    }                                                                          \
  }

  STAGE(0, 0);
  int cur = 0;
#pragma unroll 1
  for (int t = 0; t < 32; ++t) {
    // barrier: staging of buf[cur] (issued a full tile ago) is drained by the
    // implicit vmcnt(0); also fences last tile's reads of buf[cur^1].
    __syncthreads();
    if (t < 31) STAGE(cur ^ 1, (t + 1) * 64);
    const _Float16* bK = &sK[cur][0];
    const _Float16* bV = &sVT[cur][0];

    // S^T = K * Q^T over d=128 (8 k-steps). s0: kv 0..31, s1: kv 32..63.
    f16x16 s0 = {}, s1 = {};
#pragma unroll
    for (int c = 0; c < 8; ++c) {
      int off = ((c * 2 + hi) ^ sw) * 8;
      h8 a0 = *(const h8*)&bK[l31 * 128 + off];
      h8 a1 = *(const h8*)&bK[(32 + l31) * 128 + off];
      s0 = mfma32(a0, qf[c], s0);
      s1 = mfma32(a1, qf[c], s1);
    }

    // p = exp2(s) (Q pre-scaled); row-sum partial; pack adjacent-kv f16 pairs.
    // reg r of a 32x32 acc holds kv-row (r&3) + 8*(r>>2) + 4*hi.
    // => w[j] holds kv pair { 8*(j>>1) + 4*hi + 2*(j&1), +1 } for q = l31.
    uint32_t w0[8], w1[8];
#pragma unroll
    for (int j = 0; j < 8; ++j) {
      float a0 = fexp2(s0[2 * j]), b0 = fexp2(s0[2 * j + 1]);
      float a1 = fexp2(s1[2 * j]), b1 = fexp2(s1[2 * j + 1]);
      lsum += (a0 + b0) + (a1 + b1);
      w0[j] = pkrn(a0, b0);
      w1[j] = pkrn(a1, b1);
    }

    // Build PV B-frags: chunk c word wi must hold kv = c*16 + hi*8 + 2*wi+{0,1}
    // (q = l31). swap(w[4h+0], w[4h+2]) -> {word0, word2};
    // swap(w[4h+1], w[4h+3]) -> {word1, word3}.  (half h = chunk within s0/s1)
    h8 pf[4];
#pragma unroll
    for (int half = 0; half < 2; ++half) {
      u32x2 r0 = pl32swap(w0[half * 4 + 0], w0[half * 4 + 2]);
      u32x2 r1 = pl32swap(w0[half * 4 + 1], w0[half * 4 + 3]);
      u32x4 tt;
      tt[0] = r0[0];
      tt[1] = r1[0];
      tt[2] = r0[1];
      tt[3] = r1[1];
      pf[half] = __builtin_bit_cast(h8, tt);
      u32x2 r2 = pl32swap(w1[half * 4 + 0], w1[half * 4 + 2]);
      u32x2 r3 = pl32swap(w1[half * 4 + 1], w1[half * 4 + 3]);
      u32x4 uu;
      uu[0] = r2[0];
      uu[1] = r3[0];
      uu[2] = r2[1];
      uu[3] = r3[1];
      pf[2 + half] = __builtin_bit_cast(h8, uu);
    }

    // O^T[d][q] += V^T[d][kv] * P^T[kv][q]  (A = VT rows, B = P rows)
#pragma unroll
    for (int dt = 0; dt < 4; ++dt) {
#pragma unroll
      for (int c = 0; c < 4; ++c) {
        int off = ((c * 2 + hi) ^ sw) * 8;
        h8 vf = *(const h8*)&bV[(dt * 32 + l31) * 64 + off];
        oacc[dt] = mfma32(vf, pf[c], oacc[dt]);
      }
    }
    cur ^= 1;
  }
#undef STAGE

  // full row-sum: lane and lane^32 hold the same q (= l31)
  lsum += __shfl_xor(lsum, 32, 64);
  const float inv = 1.0f / lsum;

  // epilogue: transpose O^T -> O through reused sK (wave-private 8 KB)
  __syncthreads();  // all waves done reading sK/sVT
  _Float16* sO = &sK[0][0] + wave * 4096;  // [32 q][128 d], chunk-XOR swizzle
#pragma unroll
  for (int dt = 0; dt < 4; ++dt)
#pragma unroll
    for (int r = 0; r < 16; ++r) {
      int d = dt * 32 + (r & 3) + 8 * (r >> 2) + 4 * hi;
      sO[l31 * 128 + (d ^ (sw << 3))] = (_Float16)(oacc[dt][r] * inv);
    }
  const int l15 = lane & 15, gq = lane >> 4;
#pragma unroll
  for (int it = 0; it < 8; ++it) {
    int q = it * 4 + gq;  // 4 q-rows x 16 chunks per instruction
    h8 v = *(const h8*)&sO[q * 128 + ((l15 ^ (q & 7)) * 8)];
    int n = q0 + wave * 32 + q;
    *(h8*)&Oc[((size_t)(b * 2048 + n)) * 1024 + h * 128 + l15 * 8] = v;
  }
}

// ---------------------------------------------------------------------------
// out[16 x 128] tiles = Oc[16 x 1024] * WoT[128 x 1024]^T. BK=128 (8 K-steps)
// with the same dbuf single-barrier protocol. LDS 72 KB -> 2 blocks/CU,
// grid 512 = 2/CU exact.
__global__ __launch_bounds__(256, 2) void gemm_out_kernel(
    const _Float16* __restrict__ A, const _Float16* __restrict__ BT,
    float* __restrict__ outF) {
  __shared__ __align__(16) _Float16 sA[2][16 * 128];   // 2 x 4 KB
  __shared__ __align__(16) _Float16 sB[2][128 * 128];  // 2 x 32 KB
  const int tid = threadIdx.x, wave = tid >> 6, lane = tid & 63;
  const int g = lane >> 4, l15 = lane & 15, sw = l15 & 7;
  const int m0 = blockIdx.x * 16;
  f4 acc[2] = {};

// sA: 16 rows x 16 chunks (1/thread); sB: 128 rows x 16 chunks (8/thread)
#define OSTAGE(buf, kt)                                                        \
  {                                                                            \
    int rowa = tid >> 4, cka = tid & 15;                                       \
    int jga = cka ^ (rowa & 7);                                                \
    g2l16(&sA[buf][tid * 8], A + (size_t)(m0 + rowa) * 1024 + (kt) + jga * 8); \
    _Pragma("unroll") for (int i = 0; i < 8; ++i) {                            \
      int idx = i * 256 + tid;                                                 \
      int row = idx >> 4, ck = idx & 15;                                       \
      int jg = ck ^ (row & 7);                                                 \
      g2l16(&sB[buf][idx * 8], BT + (size_t)row * 1024 + (kt) + jg * 8);       \
    }                                                                          \
  }

  OSTAGE(0, 0);
  int cur = 0;
#pragma unroll 1
  for (int t = 0; t < 8; ++t) {
    __syncthreads();
    if (t < 7) OSTAGE(cur ^ 1, (t + 1) * 128);
#pragma unroll
    for (int ks = 0; ks < 4; ++ks) {
      int off = ((ks * 4 + g) ^ sw) * 8;
      h8 af = *(const h8*)&sA[cur][l15 * 128 + off];
#pragma unroll
      for (int nt = 0; nt < 2; ++nt) {
        h8 bf = *(const h8*)&sB[cur][(wave * 32 + nt * 16 + l15) * 128 + off];
        acc[nt] = mfma16(af, bf, acc[nt]);
      }
    }
    cur ^= 1;
  }
#undef OSTAGE
#pragma unroll
  for (int rg = 0; rg < 4; ++rg) {
    int m = m0 + g * 4 + rg;
#pragma unroll
    for (int nt = 0; nt < 2; ++nt)
      outF[(size_t)m * 128 + wave * 32 + nt * 16 + l15] = acc[nt][rg];
  }
}

// ---------------------------------------------------------------------------
extern "C" void kernel_launch(void* const* d_in, const int* in_sizes, int n_in,
                              void* d_out, int out_size, void* d_ws,
                              size_t ws_size, hipStream_t stream) {
  const float* x = (const float*)d_in[0];   // [4][2048][1024]
  const float* W = (const float*)d_in[1];   // [8][3][1024][128]
  const float* Wo = (const float*)d_in[2];  // [1024][128]
  float* out = (float*)d_out;               // [4][2048][128]
  char* ws = (char*)d_ws;

  _Float16* Xb = (_Float16*)(ws + 0);
  _Float16* WT = (_Float16*)(ws + 16777216);
  _Float16* WoT = (_Float16*)(ws + 23068672);
  _Float16* Qb = (_Float16*)(ws + 23330816);
  _Float16* Kb = (_Float16*)(ws + 40108032);
  _Float16* VTb = (_Float16*)(ws + 56885248);
  _Float16* Oc = (_Float16*)(ws + 73662464);

  cvt_all_kernel<<<8992, 256, 0, stream>>>(x, Xb, W, Wo, WT, WoT);
  gemm_qkv_kernel<<<dim3(64, 24), 256, 0, stream>>>(Xb, WT, Qb, Kb, VTb);
  flash_kernel<<<dim3(32, 16), 256, 0, stream>>>(Qb, Kb, VTb, Oc);
  gemm_out_kernel<<<512, 256, 0, stream>>>(Oc, WoT, out);
}